// Round 1
// baseline (194.311 us; speedup 1.0000x reference)
//
#include <hip/hip_runtime.h>

// Reference collapses: softmax over axis=-2 then summing prob over that same
// axis gives wsum == 1, so out = expm(1*logm(V)) = V = Wv^T X Wv.
// This kernel computes the batched congruence transform directly in fp32.

#define NMAT 2048      // BS*M = 32*64
#define DIN  128
#define DOUT 64
#define BLOCK 512
#define GRID  256
#define ITERS (NMAT / GRID)   // 8 matrices per block

// Dynamic LDS layout (floats): Xs[128*128] | Ws[128*64] | Ts[128*64] = 128 KiB
#define LDS_BYTES ((16384 + 8192 + 8192) * 4)

extern "C" __global__ void __launch_bounds__(BLOCK)
bimap_v_kernel(const float* __restrict__ x, const float* __restrict__ wv,
               float* __restrict__ out)
{
    extern __shared__ float lds[];
    float* Xs = lds;                    // 16384 floats (X, symmetric, unpadded)
    float* Ws = lds + 16384;            // 8192 floats  (Wv row-major [128][64])
    float* Ts = lds + 16384 + 8192;     // 8192 floats  (T = X*Wv, [128][64])

    const int t  = threadIdx.x;
    const int r0 = t >> 3;              // 0..63  (row / output-row group)
    const int c0 = (t & 7) * 8;         // 0..56  (8 output columns)

    // ---- stage Wv once: 8192 floats = 4 float4 per thread, coalesced
    {
        const float4* w4 = (const float4*)wv;
        float4* ws4 = (float4*)Ws;
#pragma unroll
        for (int i = 0; i < 4; ++i) ws4[t + i * BLOCK] = w4[t + i * BLOCK];
    }

    // ---- stage X for it=0 (straight copy; X is symmetric so we read transposed)
    float4 xr[8];
    {
        const float4* x4 = (const float4*)(x + (size_t)blockIdx.x * (DIN * DIN));
#pragma unroll
        for (int i = 0; i < 8; ++i) xr[i] = x4[t + i * BLOCK];
#pragma unroll
        for (int i = 0; i < 8; ++i) ((float4*)Xs)[t + i * BLOCK] = xr[i];
    }
    __syncthreads();

    for (int it = 0; it < ITERS; ++it) {
        const int mat = blockIdx.x + it * GRID;

        // issue prefetch of next X early; consumed after step2 (latency hidden)
        if (it + 1 < ITERS) {
            const float4* xn =
                (const float4*)(x + (size_t)(mat + GRID) * (DIN * DIN));
#pragma unroll
            for (int i = 0; i < 8; ++i) xr[i] = xn[t + i * BLOCK];
        }

        // ---- step 1: T[r][c] = sum_k X[r][k] * Wv[k][c]
        // X[r][k] read as Xs[k*128 + r] (symmetry => transposed, bank-clean)
        float a0[8], a1[8];
#pragma unroll
        for (int i = 0; i < 8; ++i) { a0[i] = 0.f; a1[i] = 0.f; }
        for (int k = 0; k < DIN; ++k) {
            const float xa = Xs[k * DIN + r0];
            const float xb = Xs[k * DIN + r0 + 64];
            const float4 wA = *(const float4*)&Ws[k * DOUT + c0];
            const float4 wB = *(const float4*)&Ws[k * DOUT + c0 + 4];
            a0[0] = fmaf(xa, wA.x, a0[0]); a0[1] = fmaf(xa, wA.y, a0[1]);
            a0[2] = fmaf(xa, wA.z, a0[2]); a0[3] = fmaf(xa, wA.w, a0[3]);
            a0[4] = fmaf(xa, wB.x, a0[4]); a0[5] = fmaf(xa, wB.y, a0[5]);
            a0[6] = fmaf(xa, wB.z, a0[6]); a0[7] = fmaf(xa, wB.w, a0[7]);
            a1[0] = fmaf(xb, wA.x, a1[0]); a1[1] = fmaf(xb, wA.y, a1[1]);
            a1[2] = fmaf(xb, wA.z, a1[2]); a1[3] = fmaf(xb, wA.w, a1[3]);
            a1[4] = fmaf(xb, wB.x, a1[4]); a1[5] = fmaf(xb, wB.y, a1[5]);
            a1[6] = fmaf(xb, wB.z, a1[6]); a1[7] = fmaf(xb, wB.w, a1[7]);
        }
        *(float4*)&Ts[r0 * DOUT + c0]            = make_float4(a0[0], a0[1], a0[2], a0[3]);
        *(float4*)&Ts[r0 * DOUT + c0 + 4]        = make_float4(a0[4], a0[5], a0[6], a0[7]);
        *(float4*)&Ts[(r0 + 64) * DOUT + c0]     = make_float4(a1[0], a1[1], a1[2], a1[3]);
        *(float4*)&Ts[(r0 + 64) * DOUT + c0 + 4] = make_float4(a1[4], a1[5], a1[6], a1[7]);
        __syncthreads();

        // ---- step 2: out[p][c] = sum_k Wv[k][p] * T[k][c]   (p = r0)
        float o[8];
#pragma unroll
        for (int i = 0; i < 8; ++i) o[i] = 0.f;
        for (int k = 0; k < DIN; ++k) {
            const float wp = Ws[k * DOUT + r0];
            const float4 tA = *(const float4*)&Ts[k * DOUT + c0];
            const float4 tB = *(const float4*)&Ts[k * DOUT + c0 + 4];
            o[0] = fmaf(wp, tA.x, o[0]); o[1] = fmaf(wp, tA.y, o[1]);
            o[2] = fmaf(wp, tA.z, o[2]); o[3] = fmaf(wp, tA.w, o[3]);
            o[4] = fmaf(wp, tB.x, o[4]); o[5] = fmaf(wp, tB.y, o[5]);
            o[6] = fmaf(wp, tB.z, o[6]); o[7] = fmaf(wp, tB.w, o[7]);
        }
        {
            float* ob = out + (size_t)mat * (DOUT * DOUT) + r0 * DOUT + c0;
            *(float4*)&ob[0] = make_float4(o[0], o[1], o[2], o[3]);
            *(float4*)&ob[4] = make_float4(o[4], o[5], o[6], o[7]);
        }
        __syncthreads();   // all Ts/Xs reads complete before overwrite

        if (it + 1 < ITERS) {
#pragma unroll
            for (int i = 0; i < 8; ++i) ((float4*)Xs)[t + i * BLOCK] = xr[i];
            __syncthreads();
        }
    }
}

extern "C" void kernel_launch(void* const* d_in, const int* in_sizes, int n_in,
                              void* d_out, int out_size, void* d_ws, size_t ws_size,
                              hipStream_t stream)
{
    const float* x  = (const float*)d_in[0];   // (32,64,128,128) fp32
    const float* wv = (const float*)d_in[3];   // (128,64) fp32
    float* out = (float*)d_out;                // (2048,64,64) fp32

    (void)in_sizes; (void)n_in; (void)d_ws; (void)ws_size; (void)out_size;

    hipFuncSetAttribute((const void*)bimap_v_kernel,
                        hipFuncAttributeMaxDynamicSharedMemorySize, LDS_BYTES);
    hipLaunchKernelGGL(bimap_v_kernel, dim3(GRID), dim3(BLOCK), LDS_BYTES,
                       stream, x, wv, out);
}

// Round 2
// 73.664 us; speedup vs baseline: 2.6378x; 2.6378x over previous
//
#include <hip/hip_runtime.h>

// out = Wv^T * X * Wv  (softmax/log-Euclidean machinery collapses: wsum == 1).
// MFMA bf16x2-split implementation:
//   stage 1: T = X*Wv        (A = X fragments straight from GLOBAL, B = Wv in regs)
//   stage 2: O = Wv^T * T    (A = Wt from LDS, B = T from LDS, both bf16 hi/lo)
// LDS = Wt hi/lo + T^T hi/lo = 64 KiB -> 2 blocks/CU.

typedef unsigned int uint;
typedef unsigned short ushort;
typedef __bf16 bf16x8 __attribute__((ext_vector_type(8)));
typedef float f32x4 __attribute__((ext_vector_type(4)));
typedef ushort ushort8 __attribute__((ext_vector_type(8)));
typedef ushort ushort4v __attribute__((ext_vector_type(4)));

#define DIN   128
#define DOUT  64
#define NMAT  2048
#define BLOCK 256
#define GRID  512
#define ITERS (NMAT / GRID)

// LDS byte offsets: rows of 128 bf16 = 256 B, XOR-swizzled
#define WT_H 0
#define WT_L 16384
#define TT_H 32768
#define TT_L 49152
#define LDS_BYTES 65536

__device__ __forceinline__ ushort f2bf(float x) {
    uint u = __builtin_bit_cast(uint, x);
    u += 0x7FFFu + ((u >> 16) & 1u);
    return (ushort)(u >> 16);
}
__device__ __forceinline__ float bf2f(ushort h) {
    uint u = ((uint)h) << 16;
    return __builtin_bit_cast(float, u);
}
// byte offset within hi/lo plane; bk = 2*k (byte index in row). XOR bits 4..6
// by row -> 16-lane column reads spread over 8 chunks; preserves 8B/16B runs.
__device__ __forceinline__ int swoff(int row, int bk) {
    return row * 256 + (bk ^ ((row & 7) << 4));
}

extern "C" __global__ void __launch_bounds__(BLOCK, 2)
spd_mfma_kernel(const float* __restrict__ x, const float* __restrict__ wv,
                float* __restrict__ out)
{
    extern __shared__ char lds[];
    const int t    = threadIdx.x;
    const int lane = t & 63;
    const int w    = t >> 6;        // wave 0..3 (owns 16 output columns)
    const int c    = lane & 15;
    const int g    = lane >> 4;

    // ---- build Wt = Wv^T (hi/lo bf16, swizzled). thread: row m=t&63, k-quarter t>>6
    {
        const int m = t & 63;
        const int kq = t >> 6;
#pragma unroll
        for (int kk = 0; kk < 32; kk += 8) {
            const int kbase = kq * 32 + kk;
            ushort8 hv, lv;
#pragma unroll
            for (int j = 0; j < 8; ++j) {
                float v = wv[(kbase + j) * DOUT + m];
                ushort h = f2bf(v);
                hv[j] = h;
                lv[j] = f2bf(v - bf2f(h));
            }
            const int off = swoff(m, 2 * kbase);
            *(ushort8*)(lds + WT_H + off) = hv;
            *(ushort8*)(lds + WT_L + off) = lv;
        }
    }

    // ---- preload Wv B-fragments for this wave's 16 columns (regs, hi/lo)
    bf16x8 Bh[4], Bl[4];
    {
        const int n = w * 16 + c;
#pragma unroll
        for (int kb = 0; kb < 4; ++kb) {
            ushort8 hv, lv;
#pragma unroll
            for (int j = 0; j < 8; ++j) {
                float v = wv[(kb * 32 + g * 8 + j) * DOUT + n];
                ushort h = f2bf(v);
                hv[j] = h;
                lv[j] = f2bf(v - bf2f(h));
            }
            Bh[kb] = __builtin_bit_cast(bf16x8, hv);
            Bl[kb] = __builtin_bit_cast(bf16x8, lv);
        }
    }
    __syncthreads();   // Wt ready

#define LOADMT(dst, mt_) do {                                                  \
        _Pragma("unroll")                                                      \
        for (int kb = 0; kb < 4; ++kb) {                                       \
            dst[2*kb]   = *(const float4*)(Xrow + (mt_)*2048 + kb*32);         \
            dst[2*kb+1] = *(const float4*)(Xrow + (mt_)*2048 + kb*32 + 4);     \
        }                                                                      \
    } while (0)

#define CVT1(e, f) { float _f = (f); ushort _h = f2bf(_f);                     \
                     hv[e] = _h; lv[e] = f2bf(_f - bf2f(_h)); }

    for (int it = 0; it < ITERS; ++it) {
        const int mat = blockIdx.x * ITERS + it;
        const float* X = x + (size_t)mat * (DIN * DIN);
        const float* Xrow = X + (size_t)c * DIN + g * 8;

        // ---- stage 1: T[:, wave's 16 cols] ; A-fragments from global
        f32x4 Tacc[8];
        float4 cur[8], nxt[8];
        LOADMT(cur, 0);
#pragma unroll
        for (int mt = 0; mt < 8; ++mt) {
            if (mt < 7) LOADMT(nxt, mt + 1);
            f32x4 acc = {0.f, 0.f, 0.f, 0.f};
#pragma unroll
            for (int kb = 0; kb < 4; ++kb) {
                ushort8 hv, lv;
                CVT1(0, cur[2*kb].x)  CVT1(1, cur[2*kb].y)
                CVT1(2, cur[2*kb].z)  CVT1(3, cur[2*kb].w)
                CVT1(4, cur[2*kb+1].x) CVT1(5, cur[2*kb+1].y)
                CVT1(6, cur[2*kb+1].z) CVT1(7, cur[2*kb+1].w)
                bf16x8 Ah = __builtin_bit_cast(bf16x8, hv);
                bf16x8 Al = __builtin_bit_cast(bf16x8, lv);
                acc = __builtin_amdgcn_mfma_f32_16x16x32_bf16(Ah, Bh[kb], acc, 0, 0, 0);
                acc = __builtin_amdgcn_mfma_f32_16x16x32_bf16(Ah, Bl[kb], acc, 0, 0, 0);
                acc = __builtin_amdgcn_mfma_f32_16x16x32_bf16(Al, Bh[kb], acc, 0, 0, 0);
            }
            Tacc[mt] = acc;
            if (mt < 7) {
#pragma unroll
                for (int q = 0; q < 8; ++q) cur[q] = nxt[q];
            }
        }

        // ---- write T^T (row n = T-col, 128 k along row) hi/lo, swizzled
        __syncthreads();   // previous matrix's stage-2 reads complete
        {
            const int n = w * 16 + c;
#pragma unroll
            for (int mt = 0; mt < 8; ++mt) {
                const int k0 = mt * 16 + g * 4;
                ushort4v hv, lv;
#pragma unroll
                for (int r = 0; r < 4; ++r) {
                    float v = Tacc[mt][r];
                    ushort h = f2bf(v);
                    hv[r] = h;
                    lv[r] = f2bf(v - bf2f(h));
                }
                const int off = swoff(n, 2 * k0);
                *(ushort4v*)(lds + TT_H + off) = hv;
                *(ushort4v*)(lds + TT_L + off) = lv;
            }
        }
        __syncthreads();

        // ---- stage 2: O = Wv^T * T ; this wave owns O[:, 16w..16w+15]
#pragma unroll
        for (int mt = 0; mt < 4; ++mt) {
            f32x4 acc = {0.f, 0.f, 0.f, 0.f};
            const int p = mt * 16 + c;   // Wt row (O row within tile = lane&15)
            const int n = w * 16 + c;    // Tt row (O col)
#pragma unroll
            for (int kb = 0; kb < 4; ++kb) {
                const int bk = 2 * (kb * 32 + g * 8);
                bf16x8 Ah = *(const bf16x8*)(lds + WT_H + swoff(p, bk));
                bf16x8 Al = *(const bf16x8*)(lds + WT_L + swoff(p, bk));
                bf16x8 Th = *(const bf16x8*)(lds + TT_H + swoff(n, bk));
                bf16x8 Tl = *(const bf16x8*)(lds + TT_L + swoff(n, bk));
                acc = __builtin_amdgcn_mfma_f32_16x16x32_bf16(Ah, Th, acc, 0, 0, 0);
                acc = __builtin_amdgcn_mfma_f32_16x16x32_bf16(Ah, Tl, acc, 0, 0, 0);
                acc = __builtin_amdgcn_mfma_f32_16x16x32_bf16(Al, Th, acc, 0, 0, 0);
            }
            float* ob = out + (size_t)mat * (DOUT * DOUT)
                      + (size_t)(mt * 16 + g * 4) * DOUT + (w * 16 + c);
#pragma unroll
            for (int r = 0; r < 4; ++r) ob[(size_t)r * DOUT] = acc[r];
        }
    }
}

extern "C" void kernel_launch(void* const* d_in, const int* in_sizes, int n_in,
                              void* d_out, int out_size, void* d_ws, size_t ws_size,
                              hipStream_t stream)
{
    const float* x  = (const float*)d_in[0];   // (32,64,128,128) fp32
    const float* wv = (const float*)d_in[3];   // (128,64) fp32
    float* out = (float*)d_out;                // (2048,64,64) fp32

    (void)in_sizes; (void)n_in; (void)d_ws; (void)ws_size; (void)out_size;

    hipFuncSetAttribute((const void*)spd_mfma_kernel,
                        hipFuncAttributeMaxDynamicSharedMemorySize, LDS_BYTES);
    hipLaunchKernelGGL(spd_mfma_kernel, dim3(GRID), dim3(BLOCK), LDS_BYTES,
                       stream, x, wv, out);
}

// Round 4
// 32.159 us; speedup vs baseline: 6.0422x; 2.2906x over previous
//
#include <hip/hip_runtime.h>

// out = Wv^T * X * Wv (softmax/log-Euclidean machinery collapses: wsum == 1).
// Pure-bf16 MFMA. X converted once (cooperatively) into LDS in A-fragment
// order with an XOR chunk swizzle; Wv/Wt fragments resident in VGPRs;
// stage1->stage2 transposition through a wave-private LDS scratch.
// All f32->bf16 conversions use the integer RNE sequence (proven in round 2).

typedef unsigned int uint;
typedef unsigned short ushort;
typedef __bf16 bf16x8 __attribute__((ext_vector_type(8)));
typedef float f32x4 __attribute__((ext_vector_type(4)));
typedef uint uint4v __attribute__((ext_vector_type(4)));
typedef uint uint2v __attribute__((ext_vector_type(2)));

#define DIN   128
#define DOUT  64
#define BLOCK 256
#define GRID  512
#define ITERS 4

#define MFMA(a, b, c) __builtin_amdgcn_mfma_f32_16x16x32_bf16((a), (b), (c), 0, 0, 0)

__device__ __forceinline__ ushort f2bf(float x) {           // RNE, exact
    uint u = __builtin_bit_cast(uint, x);
    u += 0x7FFFu + ((u >> 16) & 1u);
    return (ushort)(u >> 16);
}
__device__ __forceinline__ uint pk2(float a, float b) {     // lo16=a, hi16=b
    return (uint)f2bf(a) | ((uint)f2bf(b) << 16);
}

extern "C" __global__ void __launch_bounds__(BLOCK, 2)
spd_v4_kernel(const float* __restrict__ x, const float* __restrict__ wv,
              float* __restrict__ out)
{
    __shared__ char smem[49152];
    char* Xs = smem;                        // 32 KB: X as A-fragments, swizzled
    const int t    = threadIdx.x;
    const int lane = t & 63;
    const int w    = t >> 6;                // wave 0..3: owns cols 16w..16w+15
    const int c    = lane & 15;
    const int g    = lane >> 4;
    char* Tt = smem + 32768 + w * 4096;     // 4 KB per wave, B-fragment order

    // ---- stage-1 B fragments: B[k, n=16w+c], k = 32kb+8g+j  (regs, bf16)
    bf16x8 Bv[4];
#pragma unroll
    for (int kb = 0; kb < 4; ++kb) {
        float f[8];
#pragma unroll
        for (int j = 0; j < 8; ++j)
            f[j] = wv[(kb * 32 + g * 8 + j) * DOUT + (w * 16 + c)];
        uint4v u;
#pragma unroll
        for (int e = 0; e < 4; ++e) u[e] = pk2(f[2 * e], f[2 * e + 1]);
        Bv[kb] = __builtin_bit_cast(bf16x8, u);
    }
    // ---- stage-2 A fragments: Wt[m=16mt2+c][k] = Wv[k][16mt2+c]  (regs)
    bf16x8 Wt[4][4];
#pragma unroll
    for (int mt2 = 0; mt2 < 4; ++mt2)
#pragma unroll
        for (int kb = 0; kb < 4; ++kb) {
            float f[8];
#pragma unroll
            for (int j = 0; j < 8; ++j)
                f[j] = wv[(kb * 32 + g * 8 + j) * DOUT + (mt2 * 16 + c)];
            uint4v u;
#pragma unroll
            for (int e = 0; e < 4; ++e) u[e] = pk2(f[2 * e], f[2 * e + 1]);
            Wt[mt2][kb] = __builtin_bit_cast(bf16x8, u);
        }

    // ---- X staging geometry: thread (rr=t>>4, jj=t&15) handles
    // X[16i+rr, 8jj..8jj+7] -> frag chunk (mt=i, kb=jj>>2, g=jj&3, c=rr);
    // chunk index within tile = rr*16 + (jj^rr)  (XOR kills bank conflicts)
    const int rr = t >> 4;
    const int jj = t & 15;
    const size_t xthr = (size_t)rr * DIN + jj * 8;       // floats; + i*2048
    const int wroff = (rr * 16 + (jj ^ rr)) * 16;        // bytes;  + i*4096
    const float* xsrc = x + (size_t)blockIdx.x * ITERS * (DIN * DIN);

    // prologue: stage matrix 0
#pragma unroll
    for (int i = 0; i < 8; ++i) {
        float4 v0 = *(const float4*)(xsrc + i * 2048 + xthr);
        float4 v1 = *(const float4*)(xsrc + i * 2048 + xthr + 4);
        uint4v u;
        u[0] = pk2(v0.x, v0.y); u[1] = pk2(v0.z, v0.w);
        u[2] = pk2(v1.x, v1.y); u[3] = pk2(v1.z, v1.w);
        *(uint4v*)(Xs + i * 4096 + wroff) = u;
    }
    __syncthreads();

    // stage-1 read offsets per kb (swizzle-matched to wroff)
    int rdoff[4];
#pragma unroll
    for (int kb = 0; kb < 4; ++kb)
        rdoff[kb] = c * 256 + ((kb * 4 + g) ^ c) * 16;

    for (int it = 0; it < ITERS; ++it) {
        const int mat = blockIdx.x * ITERS + it;

        // issue next-X loads early; consumed after the post-stage2 barrier
        float4 nxt[16];
        if (it + 1 < ITERS) {
            const float* xn = xsrc + (size_t)(it + 1) * (DIN * DIN) + xthr;
#pragma unroll
            for (int i = 0; i < 8; ++i) {
                nxt[2 * i]     = *(const float4*)(xn + i * 2048);
                nxt[2 * i + 1] = *(const float4*)(xn + i * 2048 + 4);
            }
        }

        // ---- stage 1: T = X * Wv  (Tacc[mt][r] = T[16mt+4g+r, 16w+c])
        f32x4 Tacc[8];
#pragma unroll
        for (int mt = 0; mt < 8; ++mt) {
            f32x4 acc = {0.f, 0.f, 0.f, 0.f};
#pragma unroll
            for (int kb = 0; kb < 4; ++kb) {
                bf16x8 Ah = *(const bf16x8*)(Xs + mt * 4096 + rdoff[kb]);
                acc = MFMA(Ah, Bv[kb], acc);
            }
            Tacc[mt] = acc;
        }

        // ---- Tacc -> Tt (wave-private transposition into B-frag order)
        // lane holds T[k0..k0+3, 16w+c], k0 = 16mt+4g; target chunk
        // (kb'=k0>>5, sub=(k0>>3)&3, c), byte-in-chunk = (k0&7)*2
#pragma unroll
        for (int mt = 0; mt < 8; ++mt) {
            uint2v p;
            p[0] = pk2(Tacc[mt][0], Tacc[mt][1]);
            p[1] = pk2(Tacc[mt][2], Tacc[mt][3]);
            const int k0 = mt * 16 + g * 4;
            const int byte = (k0 >> 5) * 1024 + (((k0 >> 3) & 3) * 16 + c) * 16
                           + (k0 & 7) * 2;
            *(uint2v*)(Tt + byte) = p;
        }
        bf16x8 Bt[4];
#pragma unroll
        for (int kb = 0; kb < 4; ++kb)
            Bt[kb] = *(const bf16x8*)(Tt + kb * 1024 + lane * 16);

        // ---- stage 2: O = Wt * T  -> direct global stores
        float* ob = out + (size_t)mat * (DOUT * DOUT)
                  + (size_t)(g * 4) * DOUT + (w * 16 + c);
#pragma unroll
        for (int mt2 = 0; mt2 < 4; ++mt2) {
            f32x4 acc = {0.f, 0.f, 0.f, 0.f};
#pragma unroll
            for (int kb = 0; kb < 4; ++kb)
                acc = MFMA(Wt[mt2][kb], Bt[kb], acc);
#pragma unroll
            for (int r = 0; r < 4; ++r)
                ob[(size_t)(mt2 * 16 + r) * DOUT] = acc[r];
        }

        __syncthreads();              // all waves done reading Xs (stage 1)
        if (it + 1 < ITERS) {
#pragma unroll
            for (int i = 0; i < 8; ++i) {
                uint4v u;
                u[0] = pk2(nxt[2 * i].x,     nxt[2 * i].y);
                u[1] = pk2(nxt[2 * i].z,     nxt[2 * i].w);
                u[2] = pk2(nxt[2 * i + 1].x, nxt[2 * i + 1].y);
                u[3] = pk2(nxt[2 * i + 1].z, nxt[2 * i + 1].w);
                *(uint4v*)(Xs + i * 4096 + wroff) = u;
            }
            __syncthreads();          // Xs ready for next iteration
        }
    }
}

extern "C" void kernel_launch(void* const* d_in, const int* in_sizes, int n_in,
                              void* d_out, int out_size, void* d_ws, size_t ws_size,
                              hipStream_t stream)
{
    const float* x  = (const float*)d_in[0];   // (32,64,128,128) fp32
    const float* wv = (const float*)d_in[3];   // (128,64) fp32
    float* out = (float*)d_out;                // (2048,64,64) fp32

    (void)in_sizes; (void)n_in; (void)d_ws; (void)ws_size; (void)out_size;

    hipLaunchKernelGGL(spd_v4_kernel, dim3(GRID), dim3(BLOCK), 0, stream,
                       x, wv, out);
}